// Round 9
// baseline (436.335 us; speedup 1.0000x reference)
//
#include <hip/hip_runtime.h>
#include <hip/hip_bf16.h>
#include <cmath>

// Problem constants (fixed by setup_inputs)
constexpr int S = 128;   // num_states
constexpr int C = 32;    // num_chains
constexpr int N = 4096;  // num_nodes
constexpr int T = 512;   // num_iters

// Output layout (flat float32, concatenated in reference return order)
constexpr size_t OFF1 = 0;                          // log_observed_state_probs  [T,N]
constexpr size_t OFF2 = OFF1 + (size_t)T * N;       // log_observed_state_probs_ [T,C,N]
constexpr size_t OFF3 = OFF2 + (size_t)T * C * N;   // log_hidden_state_probs   [T,C,S]
constexpr size_t OFF4 = OFF3 + (size_t)T * C * S;   // log_emission             [S,N]
constexpr size_t OFF5 = OFF4 + (size_t)S * N;       // log_chain_weights        [T,C]

typedef __bf16 bf16x8 __attribute__((ext_vector_type(8)));
typedef float floatx4 __attribute__((ext_vector_type(4)));
typedef float floatx16 __attribute__((ext_vector_type(16)));

__device__ __forceinline__ void split_bf16(float p, __bf16& hi, __bf16& lo) {
    hi = (__bf16)p;
    lo = (__bf16)(p - (float)hi);
}

// ---------------------------------------------------------------------------
// Fused softmax kernel, one launch, 352 blocks x 256 threads (v5 form).
// ---------------------------------------------------------------------------
__global__ __launch_bounds__(256) void fused_softmax_kernel(
        const float* __restrict__ emis, const float* __restrict__ cw,
        const float* __restrict__ trans, const float* __restrict__ init,
        float* __restrict__ out3, float* __restrict__ out4, float* __restrict__ out5,
        __bf16* __restrict__ pET, float* __restrict__ pcw,
        __bf16* __restrict__ Rhi, __bf16* __restrict__ Rlo,
        __bf16* __restrict__ Thi, __bf16* __restrict__ Tlo,
        __bf16* __restrict__ Hhi, __bf16* __restrict__ Hlo) {
    const int b = blockIdx.x;
    const int tid = threadIdx.x;

    if (b >= 288) {   // ---- chain weights: 8 rows of 32 per block ----
        const int row = (b - 288) * 8 + (tid >> 5);
        const int j = tid & 31;
        const float v = cw[(size_t)row * C + j];
        float m = v;
#pragma unroll
        for (int o = 16; o > 0; o >>= 1) m = fmaxf(m, __shfl_xor(m, o, 64));
        float s = __expf(v - m);
#pragma unroll
        for (int o = 16; o > 0; o >>= 1) s += __shfl_xor(s, o, 64);
        const float lv = v - m - __logf(s);
        out5[(size_t)row * C + j] = lv;
        pcw[(size_t)row * C + j] = __expf(lv);
        return;
    }

    const float* x;
    int cols, row;
    if (b < 128)      { row = b;       cols = N; x = emis  + (size_t)row * N; }
    else if (b < 256) { row = b - 128; cols = S; x = trans + (size_t)row * S; }
    else              { row = b - 256; cols = S; x = init  + (size_t)row * S; }

    __shared__ float sm[4];
    __shared__ float ss[4];

    float m = -INFINITY;
    for (int j = tid; j < cols; j += 256) m = fmaxf(m, x[j]);
#pragma unroll
    for (int o = 32; o > 0; o >>= 1) m = fmaxf(m, __shfl_xor(m, o, 64));
    const int wid = tid >> 6;
    if ((tid & 63) == 0) sm[wid] = m;
    __syncthreads();
    m = fmaxf(fmaxf(sm[0], sm[1]), fmaxf(sm[2], sm[3]));

    float s = 0.f;
    for (int j = tid; j < cols; j += 256) s += __expf(x[j] - m);
#pragma unroll
    for (int o = 32; o > 0; o >>= 1) s += __shfl_xor(s, o, 64);
    if ((tid & 63) == 0) ss[wid] = s;
    __syncthreads();
    s = ss[0] + ss[1] + ss[2] + ss[3];
    const float lse = m + __logf(s);

    for (int j = tid; j < cols; j += 256) {
        const float v = x[j] - lse;
        const float p = __expf(v);
        if (b < 128) {
            out4[(size_t)row * N + j] = v;
            pET[(size_t)j * S + row] = (__bf16)p;
        } else if (b < 256) {
            __bf16 hi, lo; split_bf16(p, hi, lo);
            Rhi[(size_t)row * S + j] = hi; Rlo[(size_t)row * S + j] = lo;
            Thi[(size_t)j * S + row] = hi; Tlo[(size_t)j * S + row] = lo;
        } else {
            out3[((size_t)0 * C + row) * S + j] = v;
            __bf16 hi, lo; split_bf16(p, hi, lo);
            Hhi[(size_t)row * S + j] = hi; Hlo[(size_t)row * S + j] = lo;
        }
    }
}

// ---------------------------------------------------------------------------
// H-body for one (t, col-wave) unit — identical arithmetic to v5.
// ---------------------------------------------------------------------------
__device__ __forceinline__ void h_unit(
        int b, int w, int m, int lr, int quad,
        const __bf16* ThiS, const __bf16* TloS,
        __bf16* Hhi, __bf16* Hlo, float* out3) {
    const __bf16* Ahi = Hhi + (size_t)b * C * S;
    const __bf16* Alo = Hlo + (size_t)b * C * S;
    floatx4 acc[2][2];
#pragma unroll
    for (int mt = 0; mt < 2; mt++)
#pragma unroll
        for (int nt = 0; nt < 2; nt++) acc[mt][nt] = (floatx4)0.f;

#pragma unroll
    for (int kt = 0; kt < 4; kt++) {
        const int ko = kt * 32 + quad * 8;
        const bf16x8 ah0 = *reinterpret_cast<const bf16x8*>(&Ahi[(size_t)lr * S + ko]);
        const bf16x8 ah1 = *reinterpret_cast<const bf16x8*>(&Ahi[(size_t)(16 + lr) * S + ko]);
        const bf16x8 al0 = *reinterpret_cast<const bf16x8*>(&Alo[(size_t)lr * S + ko]);
        const bf16x8 al1 = *reinterpret_cast<const bf16x8*>(&Alo[(size_t)(16 + lr) * S + ko]);
        const bf16x8 bh0 = *reinterpret_cast<const bf16x8*>(&ThiS[(size_t)(w * 32 + lr) * S + ko]);
        const bf16x8 bh1 = *reinterpret_cast<const bf16x8*>(&ThiS[(size_t)(w * 32 + 16 + lr) * S + ko]);
        const bf16x8 bl0 = *reinterpret_cast<const bf16x8*>(&TloS[(size_t)(w * 32 + lr) * S + ko]);
        const bf16x8 bl1 = *reinterpret_cast<const bf16x8*>(&TloS[(size_t)(w * 32 + 16 + lr) * S + ko]);
        acc[0][0] = __builtin_amdgcn_mfma_f32_16x16x32_bf16(ah0, bh0, acc[0][0], 0, 0, 0);
        acc[0][0] = __builtin_amdgcn_mfma_f32_16x16x32_bf16(ah0, bl0, acc[0][0], 0, 0, 0);
        acc[0][0] = __builtin_amdgcn_mfma_f32_16x16x32_bf16(al0, bh0, acc[0][0], 0, 0, 0);
        acc[0][1] = __builtin_amdgcn_mfma_f32_16x16x32_bf16(ah0, bh1, acc[0][1], 0, 0, 0);
        acc[0][1] = __builtin_amdgcn_mfma_f32_16x16x32_bf16(ah0, bl1, acc[0][1], 0, 0, 0);
        acc[0][1] = __builtin_amdgcn_mfma_f32_16x16x32_bf16(al0, bh1, acc[0][1], 0, 0, 0);
        acc[1][0] = __builtin_amdgcn_mfma_f32_16x16x32_bf16(ah1, bh0, acc[1][0], 0, 0, 0);
        acc[1][0] = __builtin_amdgcn_mfma_f32_16x16x32_bf16(ah1, bl0, acc[1][0], 0, 0, 0);
        acc[1][0] = __builtin_amdgcn_mfma_f32_16x16x32_bf16(al1, bh0, acc[1][0], 0, 0, 0);
        acc[1][1] = __builtin_amdgcn_mfma_f32_16x16x32_bf16(ah1, bh1, acc[1][1], 0, 0, 0);
        acc[1][1] = __builtin_amdgcn_mfma_f32_16x16x32_bf16(ah1, bl1, acc[1][1], 0, 0, 0);
        acc[1][1] = __builtin_amdgcn_mfma_f32_16x16x32_bf16(al1, bh1, acc[1][1], 0, 0, 0);
    }

    const size_t t = (size_t)m + b;
#pragma unroll
    for (int mt = 0; mt < 2; mt++) {
#pragma unroll
        for (int nt = 0; nt < 2; nt++) {
#pragma unroll
            for (int reg = 0; reg < 4; reg++) {
                const int c = mt * 16 + quad * 4 + reg;
                const int n = w * 32 + nt * 16 + lr;
                const float p = acc[mt][nt][reg];
                __bf16 hi, lo; split_bf16(p, hi, lo);
                Hhi[(t * C + c) * S + n] = hi;
                Hlo[(t * C + c) * S + n] = lo;
                out3[(t * C + c) * S + n] = __logf(p);
            }
        }
    }
}

// R-squaring body for one (row-block, col-wave) unit — identical to v5.
__device__ __forceinline__ void r_unit(
        int rb, int w, int lr, int quad,
        const __bf16* RhiS, const __bf16* RloS,
        const __bf16* ThiS, const __bf16* TloS,
        __bf16* RhiD, __bf16* RloD, __bf16* ThiD, __bf16* TloD) {
    floatx4 acc[2];
    acc[0] = (floatx4)0.f; acc[1] = (floatx4)0.f;
#pragma unroll
    for (int kt = 0; kt < 4; kt++) {
        const int ko = kt * 32 + quad * 8;
        const bf16x8 ah = *reinterpret_cast<const bf16x8*>(&RhiS[(size_t)(rb * 16 + lr) * S + ko]);
        const bf16x8 al = *reinterpret_cast<const bf16x8*>(&RloS[(size_t)(rb * 16 + lr) * S + ko]);
        const bf16x8 bh0 = *reinterpret_cast<const bf16x8*>(&ThiS[(size_t)(w * 32 + lr) * S + ko]);
        const bf16x8 bh1 = *reinterpret_cast<const bf16x8*>(&ThiS[(size_t)(w * 32 + 16 + lr) * S + ko]);
        const bf16x8 bl0 = *reinterpret_cast<const bf16x8*>(&TloS[(size_t)(w * 32 + lr) * S + ko]);
        const bf16x8 bl1 = *reinterpret_cast<const bf16x8*>(&TloS[(size_t)(w * 32 + 16 + lr) * S + ko]);
        acc[0] = __builtin_amdgcn_mfma_f32_16x16x32_bf16(ah, bh0, acc[0], 0, 0, 0);
        acc[0] = __builtin_amdgcn_mfma_f32_16x16x32_bf16(ah, bl0, acc[0], 0, 0, 0);
        acc[0] = __builtin_amdgcn_mfma_f32_16x16x32_bf16(al, bh0, acc[0], 0, 0, 0);
        acc[1] = __builtin_amdgcn_mfma_f32_16x16x32_bf16(ah, bh1, acc[1], 0, 0, 0);
        acc[1] = __builtin_amdgcn_mfma_f32_16x16x32_bf16(ah, bl1, acc[1], 0, 0, 0);
        acc[1] = __builtin_amdgcn_mfma_f32_16x16x32_bf16(al, bh1, acc[1], 0, 0, 0);
    }
#pragma unroll
    for (int nt = 0; nt < 2; nt++) {
#pragma unroll
        for (int reg = 0; reg < 4; reg++) {
            const int row = rb * 16 + quad * 4 + reg;
            const int col = w * 32 + nt * 16 + lr;
            const float p = acc[nt][reg];
            __bf16 hi, lo; split_bf16(p, hi, lo);
            RhiD[(size_t)row * S + col] = hi; RloD[(size_t)row * S + col] = lo;
            ThiD[(size_t)col * S + row] = hi; TloD[(size_t)col * S + row] = lo;
        }
    }
}

// ---------------------------------------------------------------------------
// Rounds 1-5 (v5-proven launch structure, 256 thr).
// ---------------------------------------------------------------------------
__global__ __launch_bounds__(256) void h_round_kernel(
        const __bf16* __restrict__ Rhi, const __bf16* __restrict__ Rlo,
        const __bf16* __restrict__ Thi, const __bf16* __restrict__ Tlo,
        __bf16* __restrict__ Rnhi, __bf16* __restrict__ Rnlo,
        __bf16* __restrict__ Tnhi, __bf16* __restrict__ Tnlo,
        __bf16* __restrict__ Hhi, __bf16* __restrict__ Hlo,
        float* __restrict__ out3, int m, int count) {
    const int b = blockIdx.x;
    const int w = threadIdx.x >> 6;
    const int lane = threadIdx.x & 63;
    const int lr = lane & 15;
    const int quad = lane >> 4;

    if (b < count) {
        h_unit(b, w, m, lr, quad, Thi, Tlo, Hhi, Hlo, out3);
    } else {
        r_unit(b - count, w, lr, quad, Rhi, Rlo, Thi, Tlo, Rnhi, Rnlo, Tnhi, Tnlo);
    }
}

// ---------------------------------------------------------------------------
// Rounds 6-9 + obs riders (v11). Blocks [0,count) = H, [count,count+extra)
// = R-squaring (tid<256 only), rest = v9 obs blocks covering 32 t's each,
// for t-ranges finalized by PREVIOUS launches (stream order = dependency —
// no flags/spins, the v6 lesson). Riders hide ~55 us of obs under the
// ladder's idle CUs; final launch (count=extra=0) does t in [256,512).
// Obs body = v9 verbatim: LDS pET staged once, 4 t-group iterations,
// BPITCH 264 (v10 measured LDS staging is worth ~+50 us vs direct-L2).
// ---------------------------------------------------------------------------
constexpr int BPITCH = 264;  // bytes per LDS row (256 data + 8 pad)

__global__ __launch_bounds__(512, 4) void round_obs_kernel(
        const __bf16* __restrict__ Rhi, const __bf16* __restrict__ Rlo,
        const __bf16* __restrict__ Thi, const __bf16* __restrict__ Tlo,
        __bf16* __restrict__ Rnhi, __bf16* __restrict__ Rnlo,
        __bf16* __restrict__ Tnhi, __bf16* __restrict__ Tnlo,
        __bf16* __restrict__ Hhi, __bf16* __restrict__ Hlo,
        float* __restrict__ out3,
        const __bf16* __restrict__ pET, const float* __restrict__ pcw,
        float* __restrict__ out1, float* __restrict__ out2,
        int m, int count, int extra, int obs_t0) {
    __shared__ __align__(16) unsigned char Bs[128 * BPITCH];  // 33 KB
    __shared__ float sw[32][C];                               // 4 KB

    const int b = blockIdx.x;
    const int tid = threadIdx.x;

    if (b < count + extra) {      // ---- round work (256 threads active) ----
        if (tid < 256) {
            const int w = tid >> 6;
            const int lane = tid & 63;
            const int lr = lane & 15;
            const int quad = lane >> 4;
            if (b < count)
                h_unit(b, w, m, lr, quad, Thi, Tlo, Hhi, Hlo, out3);
            else
                r_unit(b - count, w, lr, quad, Rhi, Rlo, Thi, Tlo,
                       Rnhi, Rnlo, Tnhi, Tnlo);
        }
        return;
    }

    // ---- obs rider (v9 body) ----
    const int idx = b - count - extra;
    const int nblk = (idx & 31) * 128;
    const int tg = obs_t0 + (idx >> 5) * 32;

    const int w = tid >> 6;
    const int lane = tid & 63;
    const int l31 = lane & 31;
    const int half = lane >> 5;

#pragma unroll
    for (int p = 0; p < 4; p++) {
        const int i2 = p * 512 + tid;      // 0..2047
        const int row = i2 >> 4;           // 0..127
        const int c16 = i2 & 15;           // 16B chunk within row
        const float4 v = *reinterpret_cast<const float4*>(
            pET + (size_t)(nblk + row) * S + c16 * 8);
        *reinterpret_cast<float4*>(Bs + row * BPITCH + c16 * 16) = v;
    }
#pragma unroll
    for (int i = tid; i < 32 * C; i += 512)
        (&sw[0][0])[i] = pcw[(size_t)(tg + (i >> 5)) * C + (i & 31)];
    __syncthreads();

#pragma unroll 1
    for (int it = 0; it < 4; ++it) {
        const int t = tg + it * 8 + w;
        const __bf16* A = Hhi + (size_t)t * C * S;

        floatx16 acc[4];
#pragma unroll
        for (int nt = 0; nt < 4; nt++) acc[nt] = (floatx16)0.f;

#pragma unroll
        for (int ks = 0; ks < 8; ks++) {
            const int ko = ks * 16 + half * 8;
            const bf16x8 a  = *reinterpret_cast<const bf16x8*>(&A[(size_t)l31 * S + ko]);
            const bf16x8 b0 = *reinterpret_cast<const bf16x8*>(Bs + (l31) * BPITCH + ko * 2);
            const bf16x8 b1 = *reinterpret_cast<const bf16x8*>(Bs + (32 + l31) * BPITCH + ko * 2);
            const bf16x8 b2 = *reinterpret_cast<const bf16x8*>(Bs + (64 + l31) * BPITCH + ko * 2);
            const bf16x8 b3 = *reinterpret_cast<const bf16x8*>(Bs + (96 + l31) * BPITCH + ko * 2);
            acc[0] = __builtin_amdgcn_mfma_f32_32x32x16_bf16(a, b0, acc[0], 0, 0, 0);
            acc[1] = __builtin_amdgcn_mfma_f32_32x32x16_bf16(a, b1, acc[1], 0, 0, 0);
            acc[2] = __builtin_amdgcn_mfma_f32_32x32x16_bf16(a, b2, acc[2], 0, 0, 0);
            acc[3] = __builtin_amdgcn_mfma_f32_32x32x16_bf16(a, b3, acc[3], 0, 0, 0);
        }

        float p0 = 0.f, p1 = 0.f, p2 = 0.f, p3 = 0.f;
#pragma unroll
        for (int reg = 0; reg < 16; reg++) {
            const int c = (reg & 3) + 8 * (reg >> 2) + 4 * half;
            const float wv = sw[it * 8 + w][c];
            const float o0 = acc[0][reg];
            const float o1 = acc[1][reg];
            const float o2 = acc[2][reg];
            const float o3 = acc[3][reg];
            float* rowp = &out2[((size_t)t * C + c) * N + nblk + l31];
            rowp[0]  = __logf(o0);
            rowp[32] = __logf(o1);
            rowp[64] = __logf(o2);
            rowp[96] = __logf(o3);
            p0 = fmaf(wv, o0, p0);
            p1 = fmaf(wv, o1, p1);
            p2 = fmaf(wv, o2, p2);
            p3 = fmaf(wv, o3, p3);
        }
        p0 += __shfl_xor(p0, 32, 64);
        p1 += __shfl_xor(p1, 32, 64);
        p2 += __shfl_xor(p2, 32, 64);
        p3 += __shfl_xor(p3, 32, 64);
        if (half == 0) {
            float* o1p = &out1[(size_t)t * N + nblk + l31];
            o1p[0]  = __logf(p0);
            o1p[32] = __logf(p1);
            o1p[64] = __logf(p2);
            o1p[96] = __logf(p3);
        }
    }
}

// ---------------------------------------------------------------------------
extern "C" void kernel_launch(void* const* d_in, const int* in_sizes, int n_in,
                              void* d_out, int out_size, void* d_ws, size_t ws_size,
                              hipStream_t stream) {
    const float* in_init  = (const float*)d_in[0];  // [C,S]
    const float* in_cw    = (const float*)d_in[1];  // [T,C]
    const float* in_emis  = (const float*)d_in[2];  // [S,N]
    const float* in_trans = (const float*)d_in[3];  // [S,S]

    float* out = (float*)d_out;

    // Workspace layout (~9.5 MB, 256B aligned)
    char* wsb = (char*)d_ws;
    float*  ws_pcw = (float*)(wsb);                                  // 64 KB [T,C]
    __bf16* ws_pET = (__bf16*)(wsb + (64u << 10));                   // 1 MB  [N,S]
    __bf16* ws_Hhi = (__bf16*)(wsb + (1088u << 10));                 // 4 MB  [T,C,S]
    __bf16* ws_Hlo = (__bf16*)(wsb + (5184u << 10));                 // 4 MB  [T,C,S]
    __bf16* Pslot[2][4];
    for (int sl = 0; sl < 2; sl++)
        for (int pl = 0; pl < 4; pl++)
            Pslot[sl][pl] = (__bf16*)(wsb + (9280u << 10) + (size_t)(sl * 4 + pl) * (32u << 10));

    // 1) All softmaxes in one launch.
    fused_softmax_kernel<<<352, 256, 0, stream>>>(
        in_emis, in_cw, in_trans, in_init,
        out + OFF3, out + OFF4, out + OFF5,
        ws_pET, ws_pcw,
        Pslot[0][0], Pslot[0][1], Pslot[0][2], Pslot[0][3],
        ws_Hhi, ws_Hlo);

    // 2) Rounds 1-5: per-round launches (measured optimum).
    for (int r = 1; r <= 5; r++) {
        const int m = 1 << (r - 1);
        const int s = (r - 1) & 1, d = r & 1;
        h_round_kernel<<<m + 8, 256, 0, stream>>>(
            Pslot[s][0], Pslot[s][1], Pslot[s][2], Pslot[s][3],
            Pslot[d][0], Pslot[d][1], Pslot[d][2], Pslot[d][3],
            ws_Hhi, ws_Hlo, out + OFF3, m, m);
    }

    // 3) Rounds 6-9 with obs riders (t-range final per stream order),
    //    then the obs tail for t in [256,512).
    //    round r: m=2^(r-1); riders cover t in [rider_t0, rider_t0+rider_nt).
    const int rider_t0[5] = {0, 32, 64, 128, 256};
    const int rider_nt[5] = {32, 32, 64, 128, 256};
    for (int i = 0; i < 5; i++) {
        const int r = 6 + i;                 // i=4 -> pure-obs tail launch
        const int m = (i < 4) ? (1 << (r - 1)) : 0;
        const int count = (i < 4) ? m : 0;
        const int extra = (i < 3) ? 8 : 0;   // r9 and tail need no R-squaring
        const int s = (i < 4) ? ((r - 1) & 1) : 0, d = (i < 4) ? (r & 1) : 1;
        round_obs_kernel<<<count + extra + rider_nt[i], 512, 0, stream>>>(
            Pslot[s][0], Pslot[s][1], Pslot[s][2], Pslot[s][3],
            Pslot[d][0], Pslot[d][1], Pslot[d][2], Pslot[d][3],
            ws_Hhi, ws_Hlo, out + OFF3,
            ws_pET, ws_pcw, out + OFF1, out + OFF2,
            m, count, extra, rider_t0[i]);
    }
}

// Round 10
// 370.640 us; speedup vs baseline: 1.1772x; 1.1772x over previous
//
#include <hip/hip_runtime.h>
#include <hip/hip_bf16.h>
#include <cmath>

// Problem constants (fixed by setup_inputs)
constexpr int S = 128;   // num_states
constexpr int C = 32;    // num_chains
constexpr int N = 4096;  // num_nodes
constexpr int T = 512;   // num_iters

// Output layout (flat float32, concatenated in reference return order)
constexpr size_t OFF1 = 0;                          // log_observed_state_probs  [T,N]
constexpr size_t OFF2 = OFF1 + (size_t)T * N;       // log_observed_state_probs_ [T,C,N]
constexpr size_t OFF3 = OFF2 + (size_t)T * C * N;   // log_hidden_state_probs   [T,C,S]
constexpr size_t OFF4 = OFF3 + (size_t)T * C * S;   // log_emission             [S,N]
constexpr size_t OFF5 = OFF4 + (size_t)S * N;       // log_chain_weights        [T,C]

typedef __bf16 bf16x8 __attribute__((ext_vector_type(8)));
typedef float floatx4 __attribute__((ext_vector_type(4)));
typedef float floatx16 __attribute__((ext_vector_type(16)));

__device__ __forceinline__ void split_bf16(float p, __bf16& hi, __bf16& lo) {
    hi = (__bf16)p;
    lo = (__bf16)(p - (float)hi);
}

// ---------------------------------------------------------------------------
// Fused softmax kernel, one launch, 352 blocks x 256 threads (v5 form).
// ---------------------------------------------------------------------------
__global__ __launch_bounds__(256) void fused_softmax_kernel(
        const float* __restrict__ emis, const float* __restrict__ cw,
        const float* __restrict__ trans, const float* __restrict__ init,
        float* __restrict__ out3, float* __restrict__ out4, float* __restrict__ out5,
        __bf16* __restrict__ pET, float* __restrict__ pcw,
        __bf16* __restrict__ Rhi, __bf16* __restrict__ Rlo,
        __bf16* __restrict__ Thi, __bf16* __restrict__ Tlo,
        __bf16* __restrict__ Hhi, __bf16* __restrict__ Hlo) {
    const int b = blockIdx.x;
    const int tid = threadIdx.x;

    if (b >= 288) {   // ---- chain weights: 8 rows of 32 per block ----
        const int row = (b - 288) * 8 + (tid >> 5);
        const int j = tid & 31;
        const float v = cw[(size_t)row * C + j];
        float m = v;
#pragma unroll
        for (int o = 16; o > 0; o >>= 1) m = fmaxf(m, __shfl_xor(m, o, 64));
        float s = __expf(v - m);
#pragma unroll
        for (int o = 16; o > 0; o >>= 1) s += __shfl_xor(s, o, 64);
        const float lv = v - m - __logf(s);
        out5[(size_t)row * C + j] = lv;
        pcw[(size_t)row * C + j] = __expf(lv);
        return;
    }

    const float* x;
    int cols, row;
    if (b < 128)      { row = b;       cols = N; x = emis  + (size_t)row * N; }
    else if (b < 256) { row = b - 128; cols = S; x = trans + (size_t)row * S; }
    else              { row = b - 256; cols = S; x = init  + (size_t)row * S; }

    __shared__ float sm[4];
    __shared__ float ss[4];

    float m = -INFINITY;
    for (int j = tid; j < cols; j += 256) m = fmaxf(m, x[j]);
#pragma unroll
    for (int o = 32; o > 0; o >>= 1) m = fmaxf(m, __shfl_xor(m, o, 64));
    const int wid = tid >> 6;
    if ((tid & 63) == 0) sm[wid] = m;
    __syncthreads();
    m = fmaxf(fmaxf(sm[0], sm[1]), fmaxf(sm[2], sm[3]));

    float s = 0.f;
    for (int j = tid; j < cols; j += 256) s += __expf(x[j] - m);
#pragma unroll
    for (int o = 32; o > 0; o >>= 1) s += __shfl_xor(s, o, 64);
    if ((tid & 63) == 0) ss[wid] = s;
    __syncthreads();
    s = ss[0] + ss[1] + ss[2] + ss[3];
    const float lse = m + __logf(s);

    for (int j = tid; j < cols; j += 256) {
        const float v = x[j] - lse;
        const float p = __expf(v);
        if (b < 128) {
            out4[(size_t)row * N + j] = v;
            pET[(size_t)j * S + row] = (__bf16)p;
        } else if (b < 256) {
            __bf16 hi, lo; split_bf16(p, hi, lo);
            Rhi[(size_t)row * S + j] = hi; Rlo[(size_t)row * S + j] = lo;
            Thi[(size_t)j * S + row] = hi; Tlo[(size_t)j * S + row] = lo;
        } else {
            out3[((size_t)0 * C + row) * S + j] = v;
            __bf16 hi, lo; split_bf16(p, hi, lo);
            Hhi[(size_t)row * S + j] = hi; Hlo[(size_t)row * S + j] = lo;
        }
    }
}

// ---------------------------------------------------------------------------
// H-body for one (t, col-wave) unit — identical arithmetic to v5.
// ---------------------------------------------------------------------------
__device__ __forceinline__ void h_unit(
        int b, int w, int m, int lr, int quad,
        const __bf16* ThiS, const __bf16* TloS,
        __bf16* Hhi, __bf16* Hlo, float* out3) {
    const __bf16* Ahi = Hhi + (size_t)b * C * S;
    const __bf16* Alo = Hlo + (size_t)b * C * S;
    floatx4 acc[2][2];
#pragma unroll
    for (int mt = 0; mt < 2; mt++)
#pragma unroll
        for (int nt = 0; nt < 2; nt++) acc[mt][nt] = (floatx4)0.f;

#pragma unroll
    for (int kt = 0; kt < 4; kt++) {
        const int ko = kt * 32 + quad * 8;
        const bf16x8 ah0 = *reinterpret_cast<const bf16x8*>(&Ahi[(size_t)lr * S + ko]);
        const bf16x8 ah1 = *reinterpret_cast<const bf16x8*>(&Ahi[(size_t)(16 + lr) * S + ko]);
        const bf16x8 al0 = *reinterpret_cast<const bf16x8*>(&Alo[(size_t)lr * S + ko]);
        const bf16x8 al1 = *reinterpret_cast<const bf16x8*>(&Alo[(size_t)(16 + lr) * S + ko]);
        const bf16x8 bh0 = *reinterpret_cast<const bf16x8*>(&ThiS[(size_t)(w * 32 + lr) * S + ko]);
        const bf16x8 bh1 = *reinterpret_cast<const bf16x8*>(&ThiS[(size_t)(w * 32 + 16 + lr) * S + ko]);
        const bf16x8 bl0 = *reinterpret_cast<const bf16x8*>(&TloS[(size_t)(w * 32 + lr) * S + ko]);
        const bf16x8 bl1 = *reinterpret_cast<const bf16x8*>(&TloS[(size_t)(w * 32 + 16 + lr) * S + ko]);
        acc[0][0] = __builtin_amdgcn_mfma_f32_16x16x32_bf16(ah0, bh0, acc[0][0], 0, 0, 0);
        acc[0][0] = __builtin_amdgcn_mfma_f32_16x16x32_bf16(ah0, bl0, acc[0][0], 0, 0, 0);
        acc[0][0] = __builtin_amdgcn_mfma_f32_16x16x32_bf16(al0, bh0, acc[0][0], 0, 0, 0);
        acc[0][1] = __builtin_amdgcn_mfma_f32_16x16x32_bf16(ah0, bh1, acc[0][1], 0, 0, 0);
        acc[0][1] = __builtin_amdgcn_mfma_f32_16x16x32_bf16(ah0, bl1, acc[0][1], 0, 0, 0);
        acc[0][1] = __builtin_amdgcn_mfma_f32_16x16x32_bf16(al0, bh1, acc[0][1], 0, 0, 0);
        acc[1][0] = __builtin_amdgcn_mfma_f32_16x16x32_bf16(ah1, bh0, acc[1][0], 0, 0, 0);
        acc[1][0] = __builtin_amdgcn_mfma_f32_16x16x32_bf16(ah1, bl0, acc[1][0], 0, 0, 0);
        acc[1][0] = __builtin_amdgcn_mfma_f32_16x16x32_bf16(al1, bh0, acc[1][0], 0, 0, 0);
        acc[1][1] = __builtin_amdgcn_mfma_f32_16x16x32_bf16(ah1, bh1, acc[1][1], 0, 0, 0);
        acc[1][1] = __builtin_amdgcn_mfma_f32_16x16x32_bf16(ah1, bl1, acc[1][1], 0, 0, 0);
        acc[1][1] = __builtin_amdgcn_mfma_f32_16x16x32_bf16(al1, bh1, acc[1][1], 0, 0, 0);
    }

    const size_t t = (size_t)m + b;
#pragma unroll
    for (int mt = 0; mt < 2; mt++) {
#pragma unroll
        for (int nt = 0; nt < 2; nt++) {
#pragma unroll
            for (int reg = 0; reg < 4; reg++) {
                const int c = mt * 16 + quad * 4 + reg;
                const int n = w * 32 + nt * 16 + lr;
                const float p = acc[mt][nt][reg];
                __bf16 hi, lo; split_bf16(p, hi, lo);
                Hhi[(t * C + c) * S + n] = hi;
                Hlo[(t * C + c) * S + n] = lo;
                out3[(t * C + c) * S + n] = __logf(p);
            }
        }
    }
}

// R-squaring body for one (row-block, col-wave) unit — identical to v5.
__device__ __forceinline__ void r_unit(
        int rb, int w, int lr, int quad,
        const __bf16* RhiS, const __bf16* RloS,
        const __bf16* ThiS, const __bf16* TloS,
        __bf16* RhiD, __bf16* RloD, __bf16* ThiD, __bf16* TloD) {
    floatx4 acc[2];
    acc[0] = (floatx4)0.f; acc[1] = (floatx4)0.f;
#pragma unroll
    for (int kt = 0; kt < 4; kt++) {
        const int ko = kt * 32 + quad * 8;
        const bf16x8 ah = *reinterpret_cast<const bf16x8*>(&RhiS[(size_t)(rb * 16 + lr) * S + ko]);
        const bf16x8 al = *reinterpret_cast<const bf16x8*>(&RloS[(size_t)(rb * 16 + lr) * S + ko]);
        const bf16x8 bh0 = *reinterpret_cast<const bf16x8*>(&ThiS[(size_t)(w * 32 + lr) * S + ko]);
        const bf16x8 bh1 = *reinterpret_cast<const bf16x8*>(&ThiS[(size_t)(w * 32 + 16 + lr) * S + ko]);
        const bf16x8 bl0 = *reinterpret_cast<const bf16x8*>(&TloS[(size_t)(w * 32 + lr) * S + ko]);
        const bf16x8 bl1 = *reinterpret_cast<const bf16x8*>(&TloS[(size_t)(w * 32 + 16 + lr) * S + ko]);
        acc[0] = __builtin_amdgcn_mfma_f32_16x16x32_bf16(ah, bh0, acc[0], 0, 0, 0);
        acc[0] = __builtin_amdgcn_mfma_f32_16x16x32_bf16(ah, bl0, acc[0], 0, 0, 0);
        acc[0] = __builtin_amdgcn_mfma_f32_16x16x32_bf16(al, bh0, acc[0], 0, 0, 0);
        acc[1] = __builtin_amdgcn_mfma_f32_16x16x32_bf16(ah, bh1, acc[1], 0, 0, 0);
        acc[1] = __builtin_amdgcn_mfma_f32_16x16x32_bf16(ah, bl1, acc[1], 0, 0, 0);
        acc[1] = __builtin_amdgcn_mfma_f32_16x16x32_bf16(al, bh1, acc[1], 0, 0, 0);
    }
#pragma unroll
    for (int nt = 0; nt < 2; nt++) {
#pragma unroll
        for (int reg = 0; reg < 4; reg++) {
            const int row = rb * 16 + quad * 4 + reg;
            const int col = w * 32 + nt * 16 + lr;
            const float p = acc[nt][reg];
            __bf16 hi, lo; split_bf16(p, hi, lo);
            RhiD[(size_t)row * S + col] = hi; RloD[(size_t)row * S + col] = lo;
            ThiD[(size_t)col * S + row] = hi; TloD[(size_t)col * S + row] = lo;
        }
    }
}

// ---------------------------------------------------------------------------
// One H-doubling round (v5-proven launch structure; flag-sync fusion 2.3x
// slower, single-block fusion 7.5x slower, rider fusion +72 us — flat
// per-round launches are the settled optimum).
// ---------------------------------------------------------------------------
__global__ __launch_bounds__(256) void h_round_kernel(
        const __bf16* __restrict__ Rhi, const __bf16* __restrict__ Rlo,
        const __bf16* __restrict__ Thi, const __bf16* __restrict__ Tlo,
        __bf16* __restrict__ Rnhi, __bf16* __restrict__ Rnlo,
        __bf16* __restrict__ Tnhi, __bf16* __restrict__ Tnlo,
        __bf16* __restrict__ Hhi, __bf16* __restrict__ Hlo,
        float* __restrict__ out3, int m, int count) {
    const int b = blockIdx.x;
    const int w = threadIdx.x >> 6;
    const int lane = threadIdx.x & 63;
    const int lr = lane & 15;
    const int quad = lane >> 4;

    if (b < count) {
        h_unit(b, w, m, lr, quad, Thi, Tlo, Hhi, Hlo, out3);
    } else {
        r_unit(b - count, w, lr, quad, Rhi, Rlo, Thi, Tlo, Rnhi, Rnlo, Tnhi, Tnlo);
    }
}

// ---------------------------------------------------------------------------
// Observation GEMM v12: 1 KB write bursts. Block = (4 t x 256 n), 256 thr
// (4 waves), wave owns (1 t x 256 n) -> per (t,c) row the wave emits 8
// back-to-back 128 B stores = 1 KB contiguous (2x v9's 512 B); concurrent
// write streams halve to 2048. pET tile = 256 rows x 256 B = 64 KB LDS
// (static limit), pitch 256 -> T2 XOR swizzle byte ^= (row&15)<<4 on BOTH
// stage-write and read sides (2-way residual = free). pcw read direct
// (half-uniform broadcast; exonerated in v10). ~190 VGPR ->
// launch_bounds(256,2): 2 blocks/CU co-resident, 8 waves/CU.
// Theory: obs writes 268 MB at ~2.4 TB/s effective; the one untested axis
// is write-stream granularity (v4's 256->512 B was -6; doubling again).
// ---------------------------------------------------------------------------
__global__ __launch_bounds__(256, 2) void obs_mfma_kernel(
        const __bf16* __restrict__ Hb,    // [T,C,S] (hi plane)
        const __bf16* __restrict__ pET,   // [N,S]
        const float* __restrict__ pcw,    // [T,C]
        float* __restrict__ out1,
        float* __restrict__ out2) {
    __shared__ __align__(16) unsigned char Bs[256 * 256];  // 64 KB, swizzled

    const int tid = threadIdx.x;
    const int w = tid >> 6;            // wave -> t offset (0..3)
    const int lane = tid & 63;
    const int l31 = lane & 31;
    const int half = lane >> 5;
    const int nblk = blockIdx.x * 256;
    const int t = blockIdx.y * 4 + w;

    // Stage pET rows [nblk, nblk+256) into swizzled LDS: 16 chunks/thread.
#pragma unroll
    for (int p = 0; p < 16; p++) {
        const int idx = p * 256 + tid;     // 0..4095
        const int row = idx >> 4;          // 0..255
        const int c16 = idx & 15;          // 16B chunk within row
        const float4 v = *reinterpret_cast<const float4*>(
            pET + (size_t)(nblk + row) * S + c16 * 8);
        const int dst = row * 256 + ((c16 * 16) ^ ((row & 15) << 4));
        *reinterpret_cast<float4*>(Bs + dst) = v;
    }
    __syncthreads();

    const __bf16* A = Hb + (size_t)t * C * S;

    floatx16 acc[8];   // 8 n-tiles of 32 = 256 n-cols for one t
#pragma unroll
    for (int nt = 0; nt < 8; nt++) acc[nt] = (floatx16)0.f;

#pragma unroll
    for (int ks = 0; ks < 8; ks++) {
        const int ko = ks * 16 + half * 8;     // element offset in A row
        const int koB = ko * 2;                // byte offset within B row
        const bf16x8 a = *reinterpret_cast<const bf16x8*>(&A[(size_t)l31 * S + ko]);
#pragma unroll
        for (int nt = 0; nt < 8; nt++) {
            const int row = nt * 32 + l31;
            const bf16x8 b = *reinterpret_cast<const bf16x8*>(
                Bs + row * 256 + (koB ^ ((row & 15) << 4)));
            acc[nt] = __builtin_amdgcn_mfma_f32_32x32x16_bf16(a, b, acc[nt], 0, 0, 0);
        }
    }

    // Epilogue: per (t,c) row, 8 consecutive 128 B chunks = 1 KB burst.
    float pp[8];
#pragma unroll
    for (int nt = 0; nt < 8; nt++) pp[nt] = 0.f;
#pragma unroll
    for (int reg = 0; reg < 16; reg++) {
        const int c = (reg & 3) + 8 * (reg >> 2) + 4 * half;
        const float wv = pcw[(size_t)t * C + c];   // half-uniform broadcast
        float* rowp = &out2[((size_t)t * C + c) * N + nblk + l31];
#pragma unroll
        for (int nt = 0; nt < 8; nt++) {
            const float o = acc[nt][reg];
            rowp[nt * 32] = __logf(o);
            pp[nt] = fmaf(wv, o, pp[nt]);
        }
    }
#pragma unroll
    for (int nt = 0; nt < 8; nt++) pp[nt] += __shfl_xor(pp[nt], 32, 64);
    if (half == 0) {
        float* o1p = &out1[(size_t)t * N + nblk + l31];
#pragma unroll
        for (int nt = 0; nt < 8; nt++) o1p[nt * 32] = __logf(pp[nt]);
    }
}

// ---------------------------------------------------------------------------
extern "C" void kernel_launch(void* const* d_in, const int* in_sizes, int n_in,
                              void* d_out, int out_size, void* d_ws, size_t ws_size,
                              hipStream_t stream) {
    const float* in_init  = (const float*)d_in[0];  // [C,S]
    const float* in_cw    = (const float*)d_in[1];  // [T,C]
    const float* in_emis  = (const float*)d_in[2];  // [S,N]
    const float* in_trans = (const float*)d_in[3];  // [S,S]

    float* out = (float*)d_out;

    // Workspace layout (~9.5 MB, 256B aligned)
    char* wsb = (char*)d_ws;
    float*  ws_pcw = (float*)(wsb);                                  // 64 KB [T,C]
    __bf16* ws_pET = (__bf16*)(wsb + (64u << 10));                   // 1 MB  [N,S]
    __bf16* ws_Hhi = (__bf16*)(wsb + (1088u << 10));                 // 4 MB  [T,C,S]
    __bf16* ws_Hlo = (__bf16*)(wsb + (5184u << 10));                 // 4 MB  [T,C,S]
    __bf16* Pslot[2][4];
    for (int sl = 0; sl < 2; sl++)
        for (int pl = 0; pl < 4; pl++)
            Pslot[sl][pl] = (__bf16*)(wsb + (9280u << 10) + (size_t)(sl * 4 + pl) * (32u << 10));

    // 1) All softmaxes in one launch.
    fused_softmax_kernel<<<352, 256, 0, stream>>>(
        in_emis, in_cw, in_trans, in_init,
        out + OFF3, out + OFF4, out + OFF5,
        ws_pET, ws_pcw,
        Pslot[0][0], Pslot[0][1], Pslot[0][2], Pslot[0][3],
        ws_Hhi, ws_Hlo);

    // 2) H-doubling rounds: 9 per-round launches (measured optimum).
    for (int r = 1; r <= 9; r++) {
        const int m = 1 << (r - 1);
        const int count = (m < T - m) ? m : (T - m);
        const int extra = (r < 9) ? 8 : 0;
        const int s = (r - 1) & 1, d = r & 1;
        h_round_kernel<<<count + extra, 256, 0, stream>>>(
            Pslot[s][0], Pslot[s][1], Pslot[s][2], Pslot[s][3],
            Pslot[d][0], Pslot[d][1], Pslot[d][2], Pslot[d][3],
            ws_Hhi, ws_Hlo, out + OFF3, m, count);
    }

    // 3) Observation GEMM v12: 1 KB-burst epilogue, 64 KB swizzled B tile.
    obs_mfma_kernel<<<dim3(N / 256, T / 4), 256, 0, stream>>>(
        ws_Hhi, ws_pET, ws_pcw, out + OFF1, out + OFF2);
}

// Round 11
// 363.507 us; speedup vs baseline: 1.2003x; 1.0196x over previous
//
#include <hip/hip_runtime.h>
#include <hip/hip_bf16.h>
#include <cmath>

// Problem constants (fixed by setup_inputs)
constexpr int S = 128;   // num_states
constexpr int C = 32;    // num_chains
constexpr int N = 4096;  // num_nodes
constexpr int T = 512;   // num_iters

// Output layout (flat float32, concatenated in reference return order)
constexpr size_t OFF1 = 0;                          // log_observed_state_probs  [T,N]
constexpr size_t OFF2 = OFF1 + (size_t)T * N;       // log_observed_state_probs_ [T,C,N]
constexpr size_t OFF3 = OFF2 + (size_t)T * C * N;   // log_hidden_state_probs   [T,C,S]
constexpr size_t OFF4 = OFF3 + (size_t)T * C * S;   // log_emission             [S,N]
constexpr size_t OFF5 = OFF4 + (size_t)S * N;       // log_chain_weights        [T,C]

typedef __bf16 bf16x8 __attribute__((ext_vector_type(8)));
typedef float floatx4 __attribute__((ext_vector_type(4)));
typedef float floatx16 __attribute__((ext_vector_type(16)));

__device__ __forceinline__ void split_bf16(float p, __bf16& hi, __bf16& lo) {
    hi = (__bf16)p;
    lo = (__bf16)(p - (float)hi);
}

// ---------------------------------------------------------------------------
// Fused softmax kernel, one launch, 352 blocks x 256 threads (v5 form).
// ---------------------------------------------------------------------------
__global__ __launch_bounds__(256) void fused_softmax_kernel(
        const float* __restrict__ emis, const float* __restrict__ cw,
        const float* __restrict__ trans, const float* __restrict__ init,
        float* __restrict__ out3, float* __restrict__ out4, float* __restrict__ out5,
        __bf16* __restrict__ pET, float* __restrict__ pcw,
        __bf16* __restrict__ Rhi, __bf16* __restrict__ Rlo,
        __bf16* __restrict__ Thi, __bf16* __restrict__ Tlo,
        __bf16* __restrict__ Hhi, __bf16* __restrict__ Hlo) {
    const int b = blockIdx.x;
    const int tid = threadIdx.x;

    if (b >= 288) {   // ---- chain weights: 8 rows of 32 per block ----
        const int row = (b - 288) * 8 + (tid >> 5);
        const int j = tid & 31;
        const float v = cw[(size_t)row * C + j];
        float m = v;
#pragma unroll
        for (int o = 16; o > 0; o >>= 1) m = fmaxf(m, __shfl_xor(m, o, 64));
        float s = __expf(v - m);
#pragma unroll
        for (int o = 16; o > 0; o >>= 1) s += __shfl_xor(s, o, 64);
        const float lv = v - m - __logf(s);
        out5[(size_t)row * C + j] = lv;
        pcw[(size_t)row * C + j] = __expf(lv);
        return;
    }

    const float* x;
    int cols, row;
    if (b < 128)      { row = b;       cols = N; x = emis  + (size_t)row * N; }
    else if (b < 256) { row = b - 128; cols = S; x = trans + (size_t)row * S; }
    else              { row = b - 256; cols = S; x = init  + (size_t)row * S; }

    __shared__ float sm[4];
    __shared__ float ss[4];

    float m = -INFINITY;
    for (int j = tid; j < cols; j += 256) m = fmaxf(m, x[j]);
#pragma unroll
    for (int o = 32; o > 0; o >>= 1) m = fmaxf(m, __shfl_xor(m, o, 64));
    const int wid = tid >> 6;
    if ((tid & 63) == 0) sm[wid] = m;
    __syncthreads();
    m = fmaxf(fmaxf(sm[0], sm[1]), fmaxf(sm[2], sm[3]));

    float s = 0.f;
    for (int j = tid; j < cols; j += 256) s += __expf(x[j] - m);
#pragma unroll
    for (int o = 32; o > 0; o >>= 1) s += __shfl_xor(s, o, 64);
    if ((tid & 63) == 0) ss[wid] = s;
    __syncthreads();
    s = ss[0] + ss[1] + ss[2] + ss[3];
    const float lse = m + __logf(s);

    for (int j = tid; j < cols; j += 256) {
        const float v = x[j] - lse;
        const float p = __expf(v);
        if (b < 128) {
            out4[(size_t)row * N + j] = v;
            pET[(size_t)j * S + row] = (__bf16)p;
        } else if (b < 256) {
            __bf16 hi, lo; split_bf16(p, hi, lo);
            Rhi[(size_t)row * S + j] = hi; Rlo[(size_t)row * S + j] = lo;
            Thi[(size_t)j * S + row] = hi; Tlo[(size_t)j * S + row] = lo;
        } else {
            out3[((size_t)0 * C + row) * S + j] = v;
            __bf16 hi, lo; split_bf16(p, hi, lo);
            Hhi[(size_t)row * S + j] = hi; Hlo[(size_t)row * S + j] = lo;
        }
    }
}

// ---------------------------------------------------------------------------
// H-body for one (t, col-wave) unit — identical arithmetic to v5.
// ---------------------------------------------------------------------------
__device__ __forceinline__ void h_unit(
        int b, int w, int m, int lr, int quad,
        const __bf16* ThiS, const __bf16* TloS,
        __bf16* Hhi, __bf16* Hlo, float* out3) {
    const __bf16* Ahi = Hhi + (size_t)b * C * S;
    const __bf16* Alo = Hlo + (size_t)b * C * S;
    floatx4 acc[2][2];
#pragma unroll
    for (int mt = 0; mt < 2; mt++)
#pragma unroll
        for (int nt = 0; nt < 2; nt++) acc[mt][nt] = (floatx4)0.f;

#pragma unroll
    for (int kt = 0; kt < 4; kt++) {
        const int ko = kt * 32 + quad * 8;
        const bf16x8 ah0 = *reinterpret_cast<const bf16x8*>(&Ahi[(size_t)lr * S + ko]);
        const bf16x8 ah1 = *reinterpret_cast<const bf16x8*>(&Ahi[(size_t)(16 + lr) * S + ko]);
        const bf16x8 al0 = *reinterpret_cast<const bf16x8*>(&Alo[(size_t)lr * S + ko]);
        const bf16x8 al1 = *reinterpret_cast<const bf16x8*>(&Alo[(size_t)(16 + lr) * S + ko]);
        const bf16x8 bh0 = *reinterpret_cast<const bf16x8*>(&ThiS[(size_t)(w * 32 + lr) * S + ko]);
        const bf16x8 bh1 = *reinterpret_cast<const bf16x8*>(&ThiS[(size_t)(w * 32 + 16 + lr) * S + ko]);
        const bf16x8 bl0 = *reinterpret_cast<const bf16x8*>(&TloS[(size_t)(w * 32 + lr) * S + ko]);
        const bf16x8 bl1 = *reinterpret_cast<const bf16x8*>(&TloS[(size_t)(w * 32 + 16 + lr) * S + ko]);
        acc[0][0] = __builtin_amdgcn_mfma_f32_16x16x32_bf16(ah0, bh0, acc[0][0], 0, 0, 0);
        acc[0][0] = __builtin_amdgcn_mfma_f32_16x16x32_bf16(ah0, bl0, acc[0][0], 0, 0, 0);
        acc[0][0] = __builtin_amdgcn_mfma_f32_16x16x32_bf16(al0, bh0, acc[0][0], 0, 0, 0);
        acc[0][1] = __builtin_amdgcn_mfma_f32_16x16x32_bf16(ah0, bh1, acc[0][1], 0, 0, 0);
        acc[0][1] = __builtin_amdgcn_mfma_f32_16x16x32_bf16(ah0, bl1, acc[0][1], 0, 0, 0);
        acc[0][1] = __builtin_amdgcn_mfma_f32_16x16x32_bf16(al0, bh1, acc[0][1], 0, 0, 0);
        acc[1][0] = __builtin_amdgcn_mfma_f32_16x16x32_bf16(ah1, bh0, acc[1][0], 0, 0, 0);
        acc[1][0] = __builtin_amdgcn_mfma_f32_16x16x32_bf16(ah1, bl0, acc[1][0], 0, 0, 0);
        acc[1][0] = __builtin_amdgcn_mfma_f32_16x16x32_bf16(al1, bh0, acc[1][0], 0, 0, 0);
        acc[1][1] = __builtin_amdgcn_mfma_f32_16x16x32_bf16(ah1, bh1, acc[1][1], 0, 0, 0);
        acc[1][1] = __builtin_amdgcn_mfma_f32_16x16x32_bf16(ah1, bl1, acc[1][1], 0, 0, 0);
        acc[1][1] = __builtin_amdgcn_mfma_f32_16x16x32_bf16(al1, bh1, acc[1][1], 0, 0, 0);
    }

    const size_t t = (size_t)m + b;
#pragma unroll
    for (int mt = 0; mt < 2; mt++) {
#pragma unroll
        for (int nt = 0; nt < 2; nt++) {
#pragma unroll
            for (int reg = 0; reg < 4; reg++) {
                const int c = mt * 16 + quad * 4 + reg;
                const int n = w * 32 + nt * 16 + lr;
                const float p = acc[mt][nt][reg];
                __bf16 hi, lo; split_bf16(p, hi, lo);
                Hhi[(t * C + c) * S + n] = hi;
                Hlo[(t * C + c) * S + n] = lo;
                out3[(t * C + c) * S + n] = __logf(p);
            }
        }
    }
}

// R-squaring body for one (row-block, col-wave) unit — identical to v5.
__device__ __forceinline__ void r_unit(
        int rb, int w, int lr, int quad,
        const __bf16* RhiS, const __bf16* RloS,
        const __bf16* ThiS, const __bf16* TloS,
        __bf16* RhiD, __bf16* RloD, __bf16* ThiD, __bf16* TloD) {
    floatx4 acc[2];
    acc[0] = (floatx4)0.f; acc[1] = (floatx4)0.f;
#pragma unroll
    for (int kt = 0; kt < 4; kt++) {
        const int ko = kt * 32 + quad * 8;
        const bf16x8 ah = *reinterpret_cast<const bf16x8*>(&RhiS[(size_t)(rb * 16 + lr) * S + ko]);
        const bf16x8 al = *reinterpret_cast<const bf16x8*>(&RloS[(size_t)(rb * 16 + lr) * S + ko]);
        const bf16x8 bh0 = *reinterpret_cast<const bf16x8*>(&ThiS[(size_t)(w * 32 + lr) * S + ko]);
        const bf16x8 bh1 = *reinterpret_cast<const bf16x8*>(&ThiS[(size_t)(w * 32 + 16 + lr) * S + ko]);
        const bf16x8 bl0 = *reinterpret_cast<const bf16x8*>(&TloS[(size_t)(w * 32 + lr) * S + ko]);
        const bf16x8 bl1 = *reinterpret_cast<const bf16x8*>(&TloS[(size_t)(w * 32 + 16 + lr) * S + ko]);
        acc[0] = __builtin_amdgcn_mfma_f32_16x16x32_bf16(ah, bh0, acc[0], 0, 0, 0);
        acc[0] = __builtin_amdgcn_mfma_f32_16x16x32_bf16(ah, bl0, acc[0], 0, 0, 0);
        acc[0] = __builtin_amdgcn_mfma_f32_16x16x32_bf16(al, bh0, acc[0], 0, 0, 0);
        acc[1] = __builtin_amdgcn_mfma_f32_16x16x32_bf16(ah, bh1, acc[1], 0, 0, 0);
        acc[1] = __builtin_amdgcn_mfma_f32_16x16x32_bf16(ah, bl1, acc[1], 0, 0, 0);
        acc[1] = __builtin_amdgcn_mfma_f32_16x16x32_bf16(al, bh1, acc[1], 0, 0, 0);
    }
#pragma unroll
    for (int nt = 0; nt < 2; nt++) {
#pragma unroll
        for (int reg = 0; reg < 4; reg++) {
            const int row = rb * 16 + quad * 4 + reg;
            const int col = w * 32 + nt * 16 + lr;
            const float p = acc[nt][reg];
            __bf16 hi, lo; split_bf16(p, hi, lo);
            RhiD[(size_t)row * S + col] = hi; RloD[(size_t)row * S + col] = lo;
            ThiD[(size_t)col * S + row] = hi; TloD[(size_t)col * S + row] = lo;
        }
    }
}

// ---------------------------------------------------------------------------
// One H-doubling round (v5-proven launch structure; flag-sync fusion 2.3x
// slower, single-block fusion 7.5x slower, rider fusion +72 us — flat
// per-round launches are the settled optimum).
// ---------------------------------------------------------------------------
__global__ __launch_bounds__(256) void h_round_kernel(
        const __bf16* __restrict__ Rhi, const __bf16* __restrict__ Rlo,
        const __bf16* __restrict__ Thi, const __bf16* __restrict__ Tlo,
        __bf16* __restrict__ Rnhi, __bf16* __restrict__ Rnlo,
        __bf16* __restrict__ Tnhi, __bf16* __restrict__ Tnlo,
        __bf16* __restrict__ Hhi, __bf16* __restrict__ Hlo,
        float* __restrict__ out3, int m, int count) {
    const int b = blockIdx.x;
    const int w = threadIdx.x >> 6;
    const int lane = threadIdx.x & 63;
    const int lr = lane & 15;
    const int quad = lane >> 4;

    if (b < count) {
        h_unit(b, w, m, lr, quad, Thi, Tlo, Hhi, Hlo, out3);
    } else {
        r_unit(b - count, w, lr, quad, Rhi, Rlo, Thi, Tlo, Rnhi, Rnlo, Tnhi, Tnlo);
    }
}

// ---------------------------------------------------------------------------
// Observation GEMM v13 = v9 body + XCD-slab block remap.
// Theory: after sweeping bursts (256B/512B/1KB), NT, pitch, staging on/off
// (all +/-6 us), the remaining mechanism for obs's ~2.4 TB/s effective write
// rate is L2 DIRTY-LINE ADDRESS DENSITY: round-robin block->XCD dispatch
// scatters each XCD's dirty lines over the whole 268 MB out2 -> semi-random
// HBM evictions -> row-activation bound. The fill (6.2 TB/s) gives each
// block 4.5 MB contiguous. Fix: remap lid so XCD (lid&7) owns the
// contiguous t-slab [64x, 64x+64) (33 MB of out2), iterated n-fastest ->
// per-XCD dirty addresses concentrate 8x. Pure index remap, zero
// arithmetic change; mapping drift affects speed only.
// ---------------------------------------------------------------------------
constexpr int BPITCH = 264;  // bytes per LDS row (256 data + 8 pad)

__global__ __launch_bounds__(512, 4) void obs_mfma_kernel(
        const __bf16* __restrict__ Hb,    // [T,C,S] (hi plane)
        const __bf16* __restrict__ pET,   // [N,S]
        const float* __restrict__ pcw,    // [T,C]
        float* __restrict__ out1,
        float* __restrict__ out2) {
    __shared__ __align__(16) unsigned char Bs[128 * BPITCH];  // 33 KB
    __shared__ float sw[32][C];                               // 4 KB

    // XCD-slab remap: lid&7 = XCD (round-robin dispatch, m09); XCD x gets
    // by in {2x, 2x+1} (t-slab of 64), visiting bx (n) fastest.
    const int lid = blockIdx.x;          // 0..511
    const int x = lid & 7;
    const int s = lid >> 3;              // 0..63 within XCD
    const int by = x * 2 + (s >> 5);     // t-group (0..15)
    const int bx = s & 31;               // n-chunk (0..31)

    const int tid = threadIdx.x;
    const int w = tid >> 6;
    const int lane = tid & 63;
    const int l31 = lane & 31;
    const int half = lane >> 5;
    const int nblk = bx * 128;
    const int tg = by * 32;              // block covers t in [tg, tg+32)

    // Stage pET rows [nblk, nblk+128) into LDS once (coalesced 16B chunks).
#pragma unroll
    for (int p = 0; p < 4; p++) {
        const int idx = p * 512 + tid;     // 0..2047
        const int row = idx >> 4;          // 0..127
        const int c16 = idx & 15;          // 16B chunk within row
        const float4 v = *reinterpret_cast<const float4*>(
            pET + (size_t)(nblk + row) * S + c16 * 8);
        *reinterpret_cast<float4*>(Bs + row * BPITCH + c16 * 16) = v;
    }
    // Stage pcw for all 32 t's (1024 floats, 2 per thread).
#pragma unroll
    for (int i = tid; i < 32 * C; i += 512)
        (&sw[0][0])[i] = pcw[(size_t)(tg + (i >> 5)) * C + (i & 31)];
    __syncthreads();

#pragma unroll 1
    for (int it = 0; it < 4; ++it) {
        const int t = tg + it * 8 + w;     // wave owns one t per iteration
        const __bf16* A = Hb + (size_t)t * C * S;

        floatx16 acc[4];
#pragma unroll
        for (int nt = 0; nt < 4; nt++) acc[nt] = (floatx16)0.f;

#pragma unroll
        for (int ks = 0; ks < 8; ks++) {
            const int ko = ks * 16 + half * 8;
            const bf16x8 a  = *reinterpret_cast<const bf16x8*>(&A[(size_t)l31 * S + ko]);
            const bf16x8 b0 = *reinterpret_cast<const bf16x8*>(Bs + (l31) * BPITCH + ko * 2);
            const bf16x8 b1 = *reinterpret_cast<const bf16x8*>(Bs + (32 + l31) * BPITCH + ko * 2);
            const bf16x8 b2 = *reinterpret_cast<const bf16x8*>(Bs + (64 + l31) * BPITCH + ko * 2);
            const bf16x8 b3 = *reinterpret_cast<const bf16x8*>(Bs + (96 + l31) * BPITCH + ko * 2);
            acc[0] = __builtin_amdgcn_mfma_f32_32x32x16_bf16(a, b0, acc[0], 0, 0, 0);
            acc[1] = __builtin_amdgcn_mfma_f32_32x32x16_bf16(a, b1, acc[1], 0, 0, 0);
            acc[2] = __builtin_amdgcn_mfma_f32_32x32x16_bf16(a, b2, acc[2], 0, 0, 0);
            acc[3] = __builtin_amdgcn_mfma_f32_32x32x16_bf16(a, b3, acc[3], 0, 0, 0);
        }

        float p0 = 0.f, p1 = 0.f, p2 = 0.f, p3 = 0.f;
#pragma unroll
        for (int reg = 0; reg < 16; reg++) {
            const int c = (reg & 3) + 8 * (reg >> 2) + 4 * half;
            const float wv = sw[it * 8 + w][c];
            const float o0 = acc[0][reg];
            const float o1 = acc[1][reg];
            const float o2 = acc[2][reg];
            const float o3 = acc[3][reg];
            float* rowp = &out2[((size_t)t * C + c) * N + nblk + l31];
            rowp[0]  = __logf(o0);
            rowp[32] = __logf(o1);
            rowp[64] = __logf(o2);
            rowp[96] = __logf(o3);
            p0 = fmaf(wv, o0, p0);
            p1 = fmaf(wv, o1, p1);
            p2 = fmaf(wv, o2, p2);
            p3 = fmaf(wv, o3, p3);
        }
        p0 += __shfl_xor(p0, 32, 64);
        p1 += __shfl_xor(p1, 32, 64);
        p2 += __shfl_xor(p2, 32, 64);
        p3 += __shfl_xor(p3, 32, 64);
        if (half == 0) {
            float* o1p = &out1[(size_t)t * N + nblk + l31];
            o1p[0]  = __logf(p0);
            o1p[32] = __logf(p1);
            o1p[64] = __logf(p2);
            o1p[96] = __logf(p3);
        }
    }
}

// ---------------------------------------------------------------------------
extern "C" void kernel_launch(void* const* d_in, const int* in_sizes, int n_in,
                              void* d_out, int out_size, void* d_ws, size_t ws_size,
                              hipStream_t stream) {
    const float* in_init  = (const float*)d_in[0];  // [C,S]
    const float* in_cw    = (const float*)d_in[1];  // [T,C]
    const float* in_emis  = (const float*)d_in[2];  // [S,N]
    const float* in_trans = (const float*)d_in[3];  // [S,S]

    float* out = (float*)d_out;

    // Workspace layout (~9.5 MB, 256B aligned)
    char* wsb = (char*)d_ws;
    float*  ws_pcw = (float*)(wsb);                                  // 64 KB [T,C]
    __bf16* ws_pET = (__bf16*)(wsb + (64u << 10));                   // 1 MB  [N,S]
    __bf16* ws_Hhi = (__bf16*)(wsb + (1088u << 10));                 // 4 MB  [T,C,S]
    __bf16* ws_Hlo = (__bf16*)(wsb + (5184u << 10));                 // 4 MB  [T,C,S]
    __bf16* Pslot[2][4];
    for (int sl = 0; sl < 2; sl++)
        for (int pl = 0; pl < 4; pl++)
            Pslot[sl][pl] = (__bf16*)(wsb + (9280u << 10) + (size_t)(sl * 4 + pl) * (32u << 10));

    // 1) All softmaxes in one launch.
    fused_softmax_kernel<<<352, 256, 0, stream>>>(
        in_emis, in_cw, in_trans, in_init,
        out + OFF3, out + OFF4, out + OFF5,
        ws_pET, ws_pcw,
        Pslot[0][0], Pslot[0][1], Pslot[0][2], Pslot[0][3],
        ws_Hhi, ws_Hlo);

    // 2) H-doubling rounds: 9 per-round launches (measured optimum).
    for (int r = 1; r <= 9; r++) {
        const int m = 1 << (r - 1);
        const int count = (m < T - m) ? m : (T - m);
        const int extra = (r < 9) ? 8 : 0;
        const int s = (r - 1) & 1, d = r & 1;
        h_round_kernel<<<count + extra, 256, 0, stream>>>(
            Pslot[s][0], Pslot[s][1], Pslot[s][2], Pslot[s][3],
            Pslot[d][0], Pslot[d][1], Pslot[d][2], Pslot[d][3],
            ws_Hhi, ws_Hlo, out + OFF3, m, count);
    }

    // 3) Observation GEMM v13: v9 body + XCD-slab remap (1D grid).
    obs_mfma_kernel<<<512, 512, 0, stream>>>(
        ws_Hhi, ws_pET, ws_pcw, out + OFF1, out + OFF2);
}